// Round 1
// baseline (1057.186 us; speedup 1.0000x reference)
//
#include <hip/hip_runtime.h>
#include <hip/hip_bf16.h>
#include <math.h>

// Problem constants
#define N_NODES 50000
#define E_EDGES 500000
#define G_GRAPHS 128
// H = 256, NF = 64, EDGE_IN = 905 (rows: hi 0..255 | hj 256..511 | lat 512..520 | fd 521..904)

typedef _Float16 f16;
typedef _Float16 half8 __attribute__((ext_vector_type(8)));
typedef float f32x4 __attribute__((ext_vector_type(4)));

__device__ __forceinline__ float fast_silu(float x) {
    return x * (1.0f / (1.0f + __expf(-x)));
}

// ---------------------------------------------------------------------------
// Pack a [K x 256] row-major fp32 weight into MFMA-B fragment-linear f16:
// chunk (nb, kstep) of 64 lanes x 8 halfs; lane holds B[k=kstep*32+(lane>>4)*8+j][n=nb*16+(lane&15)]
// dst chunk index = nb*Ksteps + kstep; lane reads are then fully coalesced 16B/lane.
// ---------------------------------------------------------------------------
__global__ void pack_weight(const float* __restrict__ src, f16* __restrict__ dst, int Ksteps) {
    int tid = blockIdx.x * 256 + threadIdx.x;   // one thread per (chunk, lane)
    int lane = tid & 63;
    int chunk = tid >> 6;
    int kstep = chunk % Ksteps;
    int nb = chunk / Ksteps;
    if (nb >= 16) return;
    int n = nb * 16 + (lane & 15);
    int k0 = kstep * 32 + (lane >> 4) * 8;
    f16* d = dst + (size_t)tid * 8;
#pragma unroll
    for (int j = 0; j < 8; ++j)
        d[j] = (f16)src[(size_t)(k0 + j) * 256 + n];
}

// ---------------------------------------------------------------------------
// latW[g][n] = eb1[n] + sum_{i,j} (L[g] L[g]^T)[i][j] * eW1[512 + i*3 + j][n]
// ---------------------------------------------------------------------------
__global__ void prep_latw(const float* __restrict__ lat, const float* __restrict__ eW1,
                          const float* __restrict__ eb1, float* __restrict__ latW) {
    int g = blockIdx.x, n = threadIdx.x;
    float l[9];
#pragma unroll
    for (int i = 0; i < 9; ++i) l[i] = lat[g * 9 + i];
    float acc = eb1[n];
#pragma unroll
    for (int i = 0; i < 3; ++i)
#pragma unroll
        for (int j = 0; j < 3; ++j) {
            float ip = l[i*3+0]*l[j*3+0] + l[i*3+1]*l[j*3+1] + l[i*3+2]*l[j*3+2];
            acc += ip * eW1[(size_t)(512 + i*3 + j) * 256 + n];
        }
    latW[g * 256 + n] = acc;
}

// ---------------------------------------------------------------------------
// LayerNorm(h) then three GEMMs against packed weights:
//   Hh1 = ln(h) @ eW1[0:256]    (hi term)
//   Hh2 = ln(h) @ eW1[256:512]  (hj term)
//   Nh  = ln(h) @ nW1[0:256]    (node-MLP h half)
// Block = 64 rows, 256 threads (4 waves). MFMA 16x16x32 f16.
// A layout: m = lane&15, k = (lane>>4)*8 + j.  C/D: row=(lane>>4)*4+r, col=lane&15.
// ---------------------------------------------------------------------------
__global__ __launch_bounds__(256) void ln_gemm_kernel(
    const float* __restrict__ h, const float* __restrict__ gamma, const float* __restrict__ beta,
    const f16* __restrict__ Whi, const f16* __restrict__ Whj, const f16* __restrict__ Wn1,
    float* __restrict__ Hh1, float* __restrict__ Hh2, float* __restrict__ Nh)
{
    __shared__ f16 Aln[64 * 264];   // +8 pad -> 2-way LDS bank conflicts only (free)
    int tid = threadIdx.x;
    int r = tid >> 2, c4 = tid & 3;
    int row = blockIdx.x * 64 + r;
    int rowc = min(row, N_NODES - 1);
    const float* hp = h + (size_t)rowc * 256 + c4 * 64;

    float v[64];
    float s = 0.f, ss = 0.f;
#pragma unroll
    for (int i = 0; i < 16; ++i) {
        float4 x = ((const float4*)hp)[i];
        v[4*i+0] = x.x; v[4*i+1] = x.y; v[4*i+2] = x.z; v[4*i+3] = x.w;
        s  += x.x + x.y + x.z + x.w;
        ss += x.x*x.x + x.y*x.y + x.z*x.z + x.w*x.w;
    }
    // reduce over the 4 lanes of each row (lanes 4r..4r+3 are adjacent)
    s += __shfl_xor(s, 1); ss += __shfl_xor(ss, 1);
    s += __shfl_xor(s, 2); ss += __shfl_xor(ss, 2);
    float mean = s * (1.f / 256.f);
    float var  = ss * (1.f / 256.f) - mean * mean;
    float rstd = rsqrtf(var + 1e-5f);

    const float* gp = gamma + c4 * 64;
    const float* bp = beta + c4 * 64;
    f16 lnv[64];
#pragma unroll
    for (int i = 0; i < 16; ++i) {
        float4 g = ((const float4*)gp)[i];
        float4 b = ((const float4*)bp)[i];
        lnv[4*i+0] = (f16)((v[4*i+0]-mean)*rstd*g.x + b.x);
        lnv[4*i+1] = (f16)((v[4*i+1]-mean)*rstd*g.y + b.y);
        lnv[4*i+2] = (f16)((v[4*i+2]-mean)*rstd*g.z + b.z);
        lnv[4*i+3] = (f16)((v[4*i+3]-mean)*rstd*g.w + b.w);
    }
    {
        f16* dp = Aln + r * 264 + c4 * 64;
#pragma unroll
        for (int i = 0; i < 8; ++i) ((half8*)dp)[i] = ((half8*)lnv)[i];
    }
    __syncthreads();

    int lane = tid & 63, w = tid >> 6;
    int l15 = lane & 15, q = lane >> 4;
    const f16* Ws[3] = {Whi, Whj, Wn1};
    float* Os[3] = {Hh1, Hh2, Nh};
    const f32x4 z4 = {0.f, 0.f, 0.f, 0.f};

    for (int widx = 0; widx < 3; ++widx) {
        f32x4 acc[4][4];
#pragma unroll
        for (int a = 0; a < 4; ++a)
#pragma unroll
            for (int b = 0; b < 4; ++b) acc[a][b] = z4;
        const f16* W = Ws[widx];
        for (int ks = 0; ks < 8; ++ks) {
            half8 afr[4];
#pragma unroll
            for (int mb = 0; mb < 4; ++mb)
                afr[mb] = *(const half8*)(Aln + (mb*16 + l15) * 264 + ks*32 + q*8);
#pragma unroll
            for (int nbl = 0; nbl < 4; ++nbl) {
                int nb = w * 4 + nbl;
                half8 bfr = *(const half8*)(W + ((size_t)(nb*8 + ks) * 64 + lane) * 8);
#pragma unroll
                for (int mb = 0; mb < 4; ++mb)
                    acc[mb][nbl] = __builtin_amdgcn_mfma_f32_16x16x32_f16(afr[mb], bfr, acc[mb][nbl], 0, 0, 0);
            }
        }
        float* O = Os[widx];
#pragma unroll
        for (int mb = 0; mb < 4; ++mb)
#pragma unroll
            for (int rr = 0; rr < 4; ++rr) {
                int orow = blockIdx.x * 64 + mb*16 + q*4 + rr;
                if (orow < N_NODES) {
#pragma unroll
                    for (int nbl = 0; nbl < 4; ++nbl) {
                        int n = (w*4 + nbl) * 16 + l15;
                        O[(size_t)orow * 256 + n] = acc[mb][nbl][rr];
                    }
                }
            }
    }
}

// ---------------------------------------------------------------------------
// Edge kernel: 64 edges/block, 256 threads.
//  1. sinusoid embedding (v_sin in revolutions, fract-reduced) -> LDS A-tile [64][392]
//  2. MFMA K=384 vs packed W_fd
//  3. epilogue: + Hh1[src] + Hh2[dst] + latW[g] (eb1 folded in), silu -> LDS [64][264]
//  4. MFMA K=256 vs packed eW2, + eb2, silu
//  5. atomicAdd scatter into aggsum[src], cnt[src]
// ---------------------------------------------------------------------------
__global__ __launch_bounds__(256) void edge_kernel(
    const int* __restrict__ edge_index, const int* __restrict__ edge2graph,
    const float* __restrict__ frac_diff,
    const float* __restrict__ Hh1, const float* __restrict__ Hh2, const float* __restrict__ latW,
    const f16* __restrict__ Wfd, const f16* __restrict__ We2, const float* __restrict__ eb2,
    float* __restrict__ aggsum, float* __restrict__ cnt)
{
    __shared__ f16 At[64 * 392];    // 50176 B; reused (stride 264) as e1 tile for GEMM2
    __shared__ int src_s[64], dst_s[64], g_s[64];
    int tid = threadIdx.x;
    int e0 = blockIdx.x * 64;

    if (tid < 64) {
        int e = e0 + tid;
        if (e < E_EDGES) {
            src_s[tid] = edge_index[e];
            dst_s[tid] = edge_index[E_EDGES + e];
            g_s[tid]   = edge2graph[e];
        } else { src_s[tid] = 0; dst_s[tid] = 0; g_s[tid] = 0; }
    }

    // ---- sinusoid embedding: thread (m, sub) does freqs [sub*16, sub*16+16) for all 3 dims
    {
        int m = tid >> 2, sub = tid & 3;
        int e = e0 + m;
        int ec = e < E_EDGES ? e : (E_EDGES - 1);
        float xs[3];
        xs[0] = frac_diff[(size_t)ec * 3 + 0];
        xs[1] = frac_diff[(size_t)ec * 3 + 1];
        xs[2] = frac_diff[(size_t)ec * 3 + 2];
#pragma unroll
        for (int d = 0; d < 3; ++d) {
            f16 sv[16], cv[16];
#pragma unroll
            for (int i = 0; i < 16; ++i) {
                float f = (float)(sub * 16 + i);
                float t = xs[d] * f;
                float rev = t - floorf(t);             // v_sin takes revolutions; fract to [0,1)
                sv[i] = (f16)__builtin_amdgcn_sinf(rev);
                cv[i] = (f16)__builtin_amdgcn_cosf(rev);
            }
            f16* ps = At + m * 392 + d * 64 + sub * 16;
            ((half8*)ps)[0] = ((half8*)sv)[0];
            ((half8*)ps)[1] = ((half8*)sv)[1];
            f16* pc = ps + 192;
            ((half8*)pc)[0] = ((half8*)cv)[0];
            ((half8*)pc)[1] = ((half8*)cv)[1];
        }
    }
    __syncthreads();

    int lane = tid & 63, w = tid >> 6;
    int l15 = lane & 15, q = lane >> 4;
    const f32x4 z4 = {0.f, 0.f, 0.f, 0.f};

    // ---- GEMM1: [64 x 384] @ [384 x 256]
    f32x4 acc[4][4];
#pragma unroll
    for (int a = 0; a < 4; ++a)
#pragma unroll
        for (int b = 0; b < 4; ++b) acc[a][b] = z4;
    for (int ks = 0; ks < 12; ++ks) {
        half8 afr[4];
#pragma unroll
        for (int mb = 0; mb < 4; ++mb)
            afr[mb] = *(const half8*)(At + (mb*16 + l15) * 392 + ks*32 + q*8);
#pragma unroll
        for (int nbl = 0; nbl < 4; ++nbl) {
            int nb = w * 4 + nbl;
            half8 bfr = *(const half8*)(Wfd + ((size_t)(nb*12 + ks) * 64 + lane) * 8);
#pragma unroll
            for (int mb = 0; mb < 4; ++mb)
                acc[mb][nbl] = __builtin_amdgcn_mfma_f32_16x16x32_f16(afr[mb], bfr, acc[mb][nbl], 0, 0, 0);
        }
    }
    __syncthreads();   // everyone done reading At before we overwrite it

    // ---- epilogue 1: gather node/graph terms, silu, write e1 (f16) to LDS (stride 264)
#pragma unroll
    for (int mb = 0; mb < 4; ++mb)
#pragma unroll
        for (int rr = 0; rr < 4; ++rr) {
            int mm = mb*16 + q*4 + rr;
            int sidx = src_s[mm], didx = dst_s[mm], gidx = g_s[mm];
            const float* p1 = Hh1  + (size_t)sidx * 256;
            const float* p2 = Hh2  + (size_t)didx * 256;
            const float* p3 = latW + (size_t)gidx * 256;
#pragma unroll
            for (int nbl = 0; nbl < 4; ++nbl) {
                int n = (w*4 + nbl) * 16 + l15;
                float vv = acc[mb][nbl][rr] + p1[n] + p2[n] + p3[n];   // eb1 already in latW
                At[mm * 264 + n] = (f16)fast_silu(vv);
            }
        }
    __syncthreads();

    // ---- GEMM2: [64 x 256] @ [256 x 256]
    f32x4 acc2[4][4];
#pragma unroll
    for (int a = 0; a < 4; ++a)
#pragma unroll
        for (int b = 0; b < 4; ++b) acc2[a][b] = z4;
    for (int ks = 0; ks < 8; ++ks) {
        half8 afr[4];
#pragma unroll
        for (int mb = 0; mb < 4; ++mb)
            afr[mb] = *(const half8*)(At + (mb*16 + l15) * 264 + ks*32 + q*8);
#pragma unroll
        for (int nbl = 0; nbl < 4; ++nbl) {
            int nb = w * 4 + nbl;
            half8 bfr = *(const half8*)(We2 + ((size_t)(nb*8 + ks) * 64 + lane) * 8);
#pragma unroll
            for (int mb = 0; mb < 4; ++mb)
                acc2[mb][nbl] = __builtin_amdgcn_mfma_f32_16x16x32_f16(afr[mb], bfr, acc2[mb][nbl], 0, 0, 0);
        }
    }

    // ---- epilogue 2: silu(+eb2) and scatter-add
#pragma unroll
    for (int mb = 0; mb < 4; ++mb)
#pragma unroll
        for (int rr = 0; rr < 4; ++rr) {
            int mm = mb*16 + q*4 + rr;
            if (e0 + mm < E_EDGES) {
                int sidx = src_s[mm];
                float* pa = aggsum + (size_t)sidx * 256;
#pragma unroll
                for (int nbl = 0; nbl < 4; ++nbl) {
                    int n = (w*4 + nbl) * 16 + l15;
                    float vv = fast_silu(acc2[mb][nbl][rr] + eb2[n]);
                    atomicAdd(pa + n, vv);
                }
            }
        }
    if (tid < 64 && e0 + tid < E_EDGES)
        atomicAdd(cnt + src_s[tid], 1.0f);
}

// ---------------------------------------------------------------------------
// Node post: agg = aggsum / max(cnt,1); t = silu(Nh + agg@Wn1a + nb1);
// out = h + silu(t@Wn2 + nb2)
// ---------------------------------------------------------------------------
__global__ __launch_bounds__(256) void node_post_kernel(
    const float* __restrict__ aggsum, const float* __restrict__ cnt,
    const float* __restrict__ Nh, const f16* __restrict__ Wn1a, const f16* __restrict__ Wn2,
    const float* __restrict__ nb1, const float* __restrict__ nb2,
    const float* __restrict__ h, float* __restrict__ out)
{
    __shared__ f16 T[64 * 264];
    int tid = threadIdx.x;
    int r = tid >> 2, c4 = tid & 3;
    int row = blockIdx.x * 64 + r;
    int rowc = min(row, N_NODES - 1);
    float inv = 1.f / fmaxf(cnt[rowc], 1.f);
    {
        const float* ap = aggsum + (size_t)rowc * 256 + c4 * 64;
        f16 av[64];
#pragma unroll
        for (int i = 0; i < 16; ++i) {
            float4 x = ((const float4*)ap)[i];
            av[4*i+0] = (f16)(x.x * inv);
            av[4*i+1] = (f16)(x.y * inv);
            av[4*i+2] = (f16)(x.z * inv);
            av[4*i+3] = (f16)(x.w * inv);
        }
        f16* dp = T + r * 264 + c4 * 64;
#pragma unroll
        for (int i = 0; i < 8; ++i) ((half8*)dp)[i] = ((half8*)av)[i];
    }
    __syncthreads();

    int lane = tid & 63, w = tid >> 6;
    int l15 = lane & 15, q = lane >> 4;
    const f32x4 z4 = {0.f, 0.f, 0.f, 0.f};

    f32x4 acc[4][4];
#pragma unroll
    for (int a = 0; a < 4; ++a)
#pragma unroll
        for (int b = 0; b < 4; ++b) acc[a][b] = z4;
    for (int ks = 0; ks < 8; ++ks) {
        half8 afr[4];
#pragma unroll
        for (int mb = 0; mb < 4; ++mb)
            afr[mb] = *(const half8*)(T + (mb*16 + l15) * 264 + ks*32 + q*8);
#pragma unroll
        for (int nbl = 0; nbl < 4; ++nbl) {
            int nb = w * 4 + nbl;
            half8 bfr = *(const half8*)(Wn1a + ((size_t)(nb*8 + ks) * 64 + lane) * 8);
#pragma unroll
            for (int mb = 0; mb < 4; ++mb)
                acc[mb][nbl] = __builtin_amdgcn_mfma_f32_16x16x32_f16(afr[mb], bfr, acc[mb][nbl], 0, 0, 0);
        }
    }
    __syncthreads();

    // t = silu(Nh + agg@Wn1a + nb1) -> back into T
#pragma unroll
    for (int mb = 0; mb < 4; ++mb)
#pragma unroll
        for (int rr = 0; rr < 4; ++rr) {
            int orow = blockIdx.x * 64 + mb*16 + q*4 + rr;
            int orc = min(orow, N_NODES - 1);
            const float* np = Nh + (size_t)orc * 256;
            int mm = mb*16 + q*4 + rr;
#pragma unroll
            for (int nbl = 0; nbl < 4; ++nbl) {
                int n = (w*4 + nbl) * 16 + l15;
                float tv = fast_silu(acc[mb][nbl][rr] + np[n] + nb1[n]);
                T[mm * 264 + n] = (f16)tv;
            }
        }
    __syncthreads();

    f32x4 acc2[4][4];
#pragma unroll
    for (int a = 0; a < 4; ++a)
#pragma unroll
        for (int b = 0; b < 4; ++b) acc2[a][b] = z4;
    for (int ks = 0; ks < 8; ++ks) {
        half8 afr[4];
#pragma unroll
        for (int mb = 0; mb < 4; ++mb)
            afr[mb] = *(const half8*)(T + (mb*16 + l15) * 264 + ks*32 + q*8);
#pragma unroll
        for (int nbl = 0; nbl < 4; ++nbl) {
            int nb = w * 4 + nbl;
            half8 bfr = *(const half8*)(Wn2 + ((size_t)(nb*8 + ks) * 64 + lane) * 8);
#pragma unroll
            for (int mb = 0; mb < 4; ++mb)
                acc2[mb][nbl] = __builtin_amdgcn_mfma_f32_16x16x32_f16(afr[mb], bfr, acc2[mb][nbl], 0, 0, 0);
        }
    }

#pragma unroll
    for (int mb = 0; mb < 4; ++mb)
#pragma unroll
        for (int rr = 0; rr < 4; ++rr) {
            int orow = blockIdx.x * 64 + mb*16 + q*4 + rr;
            if (orow < N_NODES) {
#pragma unroll
                for (int nbl = 0; nbl < 4; ++nbl) {
                    int n = (w*4 + nbl) * 16 + l15;
                    float ov = h[(size_t)orow * 256 + n] + fast_silu(acc2[mb][nbl][rr] + nb2[n]);
                    out[(size_t)orow * 256 + n] = ov;
                }
            }
        }
}

// ---------------------------------------------------------------------------
extern "C" void kernel_launch(void* const* d_in, const int* in_sizes, int n_in,
                              void* d_out, int out_size, void* d_ws, size_t ws_size,
                              hipStream_t stream) {
    const float* h          = (const float*)d_in[0];
    // d_in[1] frac_coords: unused by reference
    const float* lattices   = (const float*)d_in[2];
    const int*   edge_index = (const int*)d_in[3];
    const int*   edge2graph = (const int*)d_in[4];
    const float* frac_diff  = (const float*)d_in[5];
    const float* ln_gamma   = (const float*)d_in[6];
    const float* ln_beta    = (const float*)d_in[7];
    const float* eW1        = (const float*)d_in[8];
    const float* eb1        = (const float*)d_in[9];
    const float* eW2        = (const float*)d_in[10];
    const float* eb2        = (const float*)d_in[11];
    const float* nW1        = (const float*)d_in[12];
    const float* nb1        = (const float*)d_in[13];
    const float* nW2        = (const float*)d_in[14];
    const float* nb2        = (const float*)d_in[15];
    float* out = (float*)d_out;
    float* ws  = (float*)d_ws;

    // workspace layout (float offsets)
    float* Hh1    = ws;                   // 12,800,000
    float* Hh2    = ws + 12800000;        // 12,800,000
    float* Nh     = ws + 25600000;        // 12,800,000
    float* aggsum = ws + 38400000;        // 12,800,000
    float* cntf   = ws + 51200000;        // 50,048
    float* latW   = ws + 51250048;        // 32,768
    f16*   packs  = (f16*)(ws + 51282816);
    f16* Wfd  = packs;            // 98,304 halfs (K=384)
    f16* Whi  = Wfd  + 98304;     // 65,536
    f16* Whj  = Whi  + 65536;
    f16* We2  = Whj  + 65536;
    f16* Wn1h = We2  + 65536;
    f16* Wn1a = Wn1h + 65536;
    f16* Wn2  = Wn1a + 65536;
    // total: 205,131,264 + 983,040 bytes
    if (ws_size < (size_t)206114304) return;

    hipMemsetAsync(aggsum, 0, (size_t)(12800000 + 50048) * sizeof(float), stream);

    pack_weight<<<48, 256, 0, stream>>>(eW1 + 521 * 256, Wfd, 12);
    pack_weight<<<32, 256, 0, stream>>>(eW1,             Whi, 8);
    pack_weight<<<32, 256, 0, stream>>>(eW1 + 256 * 256, Whj, 8);
    pack_weight<<<32, 256, 0, stream>>>(eW2,             We2, 8);
    pack_weight<<<32, 256, 0, stream>>>(nW1,             Wn1h, 8);
    pack_weight<<<32, 256, 0, stream>>>(nW1 + 256 * 256, Wn1a, 8);
    pack_weight<<<32, 256, 0, stream>>>(nW2,             Wn2, 8);
    prep_latw<<<G_GRAPHS, 256, 0, stream>>>(lattices, eW1, eb1, latW);

    ln_gemm_kernel<<<(N_NODES + 63) / 64, 256, 0, stream>>>(
        h, ln_gamma, ln_beta, Whi, Whj, Wn1h, Hh1, Hh2, Nh);

    edge_kernel<<<(E_EDGES + 63) / 64, 256, 0, stream>>>(
        edge_index, edge2graph, frac_diff, Hh1, Hh2, latW, Wfd, We2, eb2, aggsum, cntf);

    node_post_kernel<<<(N_NODES + 63) / 64, 256, 0, stream>>>(
        aggsum, cntf, Nh, Wn1a, Wn2, nb1, nb2, h, out);
}

// Round 2
// 1044.439 us; speedup vs baseline: 1.0122x; 1.0122x over previous
//
#include <hip/hip_runtime.h>
#include <hip/hip_bf16.h>
#include <math.h>

// Problem constants
#define N_NODES 50000
#define E_EDGES 500000
#define G_GRAPHS 128
#define N_PAD 50176   // 196*256, padded node count for scan
// H = 256, NF = 64, EDGE_IN = 905 (rows: hi 0..255 | hj 256..511 | lat 512..520 | fd 521..904)

typedef _Float16 f16;
typedef _Float16 half8 __attribute__((ext_vector_type(8)));
typedef float f32x4 __attribute__((ext_vector_type(4)));

__device__ __forceinline__ float fast_silu(float x) {
    return x * (1.0f / (1.0f + __expf(-x)));
}

// ---------------------------------------------------------------------------
// Pack a [K x 256] row-major fp32 weight into MFMA-B fragment-linear f16.
// ---------------------------------------------------------------------------
__global__ void pack_weight(const float* __restrict__ src, f16* __restrict__ dst, int Ksteps) {
    int tid = blockIdx.x * 256 + threadIdx.x;
    int lane = tid & 63;
    int chunk = tid >> 6;
    int kstep = chunk % Ksteps;
    int nb = chunk / Ksteps;
    if (nb >= 16) return;
    int n = nb * 16 + (lane & 15);
    int k0 = kstep * 32 + (lane >> 4) * 8;
    f16* d = dst + (size_t)tid * 8;
#pragma unroll
    for (int j = 0; j < 8; ++j)
        d[j] = (f16)src[(size_t)(k0 + j) * 256 + n];
}

// ---------------------------------------------------------------------------
// latW[g][n] = eb1[n] + sum_{i,j} (L L^T)[i][j] * eW1[512 + i*3 + j][n]
// ---------------------------------------------------------------------------
__global__ void prep_latw(const float* __restrict__ lat, const float* __restrict__ eW1,
                          const float* __restrict__ eb1, float* __restrict__ latW) {
    int g = blockIdx.x, n = threadIdx.x;
    float l[9];
#pragma unroll
    for (int i = 0; i < 9; ++i) l[i] = lat[g * 9 + i];
    float acc = eb1[n];
#pragma unroll
    for (int i = 0; i < 3; ++i)
#pragma unroll
        for (int j = 0; j < 3; ++j) {
            float ip = l[i*3+0]*l[j*3+0] + l[i*3+1]*l[j*3+1] + l[i*3+2]*l[j*3+2];
            acc += ip * eW1[(size_t)(512 + i*3 + j) * 256 + n];
        }
    latW[g * 256 + n] = acc;
}

// ---------------------------------------------------------------------------
// CSR build: histogram -> single-block scan -> position scatter
// ---------------------------------------------------------------------------
__global__ void hist_kernel(const int* __restrict__ ei, int* __restrict__ cnt) {
    int e = blockIdx.x * 256 + threadIdx.x;
    if (e < E_EDGES) atomicAdd(cnt + ei[e], 1);
}

__global__ __launch_bounds__(1024) void scan_kernel(const int* __restrict__ cnt, int* __restrict__ off) {
    __shared__ int wsum[16], wpre[16];
    __shared__ int stot;
    int t = threadIdx.x, lane = t & 63, w = t >> 6;
    int running = 0;
    for (int c = 0; c < N_PAD; c += 1024) {
        int v = cnt[c + t];
        int x = v;
#pragma unroll
        for (int d = 1; d < 64; d <<= 1) { int nn = __shfl_up(x, d); if (lane >= d) x += nn; }
        if (lane == 63) wsum[w] = x;
        __syncthreads();
        if (t == 0) { int a = 0; for (int i = 0; i < 16; ++i) { wpre[i] = a; a += wsum[i]; } stot = a; }
        __syncthreads();
        off[c + t] = running + wpre[w] + x - v;   // exclusive
        running += stot;
        __syncthreads();
    }
}

__global__ void pos_kernel(const int* __restrict__ ei, const int* __restrict__ off,
                           int* __restrict__ tmp, int* __restrict__ sorted_e) {
    int e = blockIdx.x * 256 + threadIdx.x;
    if (e >= E_EDGES) return;
    int s = ei[e];
    int p = off[s] + atomicAdd(tmp + s, 1);
    sorted_e[p] = e;
}

// ---------------------------------------------------------------------------
// LayerNorm(h) then three GEMMs -> f16 outputs Hh1/Hh2/Nh
// ---------------------------------------------------------------------------
__global__ __launch_bounds__(256) void ln_gemm_kernel(
    const float* __restrict__ h, const float* __restrict__ gamma, const float* __restrict__ beta,
    const f16* __restrict__ Whi, const f16* __restrict__ Whj, const f16* __restrict__ Wn1,
    f16* __restrict__ Hh1, f16* __restrict__ Hh2, f16* __restrict__ Nh)
{
    __shared__ f16 Aln[64 * 264];
    int tid = threadIdx.x;
    int r = tid >> 2, c4 = tid & 3;
    int row = blockIdx.x * 64 + r;
    int rowc = min(row, N_NODES - 1);
    const float* hp = h + (size_t)rowc * 256 + c4 * 64;

    float v[64];
    float s = 0.f, ss = 0.f;
#pragma unroll
    for (int i = 0; i < 16; ++i) {
        float4 x = ((const float4*)hp)[i];
        v[4*i+0] = x.x; v[4*i+1] = x.y; v[4*i+2] = x.z; v[4*i+3] = x.w;
        s  += x.x + x.y + x.z + x.w;
        ss += x.x*x.x + x.y*x.y + x.z*x.z + x.w*x.w;
    }
    s += __shfl_xor(s, 1); ss += __shfl_xor(ss, 1);
    s += __shfl_xor(s, 2); ss += __shfl_xor(ss, 2);
    float mean = s * (1.f / 256.f);
    float var  = ss * (1.f / 256.f) - mean * mean;
    float rstd = rsqrtf(var + 1e-5f);

    const float* gp = gamma + c4 * 64;
    const float* bp = beta + c4 * 64;
    f16 lnv[64];
#pragma unroll
    for (int i = 0; i < 16; ++i) {
        float4 g = ((const float4*)gp)[i];
        float4 b = ((const float4*)bp)[i];
        lnv[4*i+0] = (f16)((v[4*i+0]-mean)*rstd*g.x + b.x);
        lnv[4*i+1] = (f16)((v[4*i+1]-mean)*rstd*g.y + b.y);
        lnv[4*i+2] = (f16)((v[4*i+2]-mean)*rstd*g.z + b.z);
        lnv[4*i+3] = (f16)((v[4*i+3]-mean)*rstd*g.w + b.w);
    }
    {
        f16* dp = Aln + r * 264 + c4 * 64;
#pragma unroll
        for (int i = 0; i < 8; ++i) ((half8*)dp)[i] = ((half8*)lnv)[i];
    }
    __syncthreads();

    int lane = tid & 63, w = tid >> 6;
    int l15 = lane & 15, q = lane >> 4;
    const f16* Ws[3] = {Whi, Whj, Wn1};
    f16* Os[3] = {Hh1, Hh2, Nh};
    const f32x4 z4 = {0.f, 0.f, 0.f, 0.f};

    for (int widx = 0; widx < 3; ++widx) {
        f32x4 acc[4][4];
#pragma unroll
        for (int a = 0; a < 4; ++a)
#pragma unroll
            for (int b = 0; b < 4; ++b) acc[a][b] = z4;
        const f16* W = Ws[widx];
        for (int ks = 0; ks < 8; ++ks) {
            half8 afr[4];
#pragma unroll
            for (int mb = 0; mb < 4; ++mb)
                afr[mb] = *(const half8*)(Aln + (mb*16 + l15) * 264 + ks*32 + q*8);
#pragma unroll
            for (int nbl = 0; nbl < 4; ++nbl) {
                int nb = w * 4 + nbl;
                half8 bfr = *(const half8*)(W + ((size_t)(nb*8 + ks) * 64 + lane) * 8);
#pragma unroll
                for (int mb = 0; mb < 4; ++mb)
                    acc[mb][nbl] = __builtin_amdgcn_mfma_f32_16x16x32_f16(afr[mb], bfr, acc[mb][nbl], 0, 0, 0);
            }
        }
        f16* O = Os[widx];
#pragma unroll
        for (int mb = 0; mb < 4; ++mb)
#pragma unroll
            for (int rr = 0; rr < 4; ++rr) {
                int orow = blockIdx.x * 64 + mb*16 + q*4 + rr;
                if (orow < N_NODES) {
#pragma unroll
                    for (int nbl = 0; nbl < 4; ++nbl) {
                        int n = (w*4 + nbl) * 16 + l15;
                        O[(size_t)orow * 256 + n] = (f16)acc[mb][nbl][rr];
                    }
                }
            }
    }
}

// ---------------------------------------------------------------------------
// Edge kernel v2: consumes edges sorted by src.
//  1. sinusoids -> LDS A-tile  2. MFMA K=384  3. +Hh1[src]+Hh2[dst]+latW[g], silu
//  4. MFMA K=256, +eb2, silu -> LDS  5. segmented (by src) LDS reduce, one
//     fp32 atomicAdd per (segment,col) -- ~9x fewer atomics than per-edge.
// ---------------------------------------------------------------------------
__global__ __launch_bounds__(256) void edge_kernel(
    const int* __restrict__ sorted_e,
    const int* __restrict__ edge_index, const int* __restrict__ edge2graph,
    const float* __restrict__ frac_diff,
    const f16* __restrict__ Hh1, const f16* __restrict__ Hh2, const float* __restrict__ latW,
    const f16* __restrict__ Wfd, const f16* __restrict__ We2, const float* __restrict__ eb2,
    float* __restrict__ aggsum)
{
    __shared__ f16 At[64 * 392];          // 50176 B; reused (stride 264) downstream
    __shared__ int e_s[64], src_s[64], dst_s[64], g_s[64], srcr[64];
    int tid = threadIdx.x;
    int e0 = blockIdx.x * 64;

    if (tid < 64) {
        int slot = e0 + tid;
        int e = (slot < E_EDGES) ? sorted_e[slot] : -1;
        int ec = e < 0 ? 0 : e;
        int sv = edge_index[ec];
        e_s[tid]   = ec;
        src_s[tid] = sv;
        dst_s[tid] = edge_index[E_EDGES + ec];
        g_s[tid]   = edge2graph[ec];
        srcr[tid]  = (e < 0) ? -1 : sv;   // sentinel for reduce
    }
    __syncthreads();

    // ---- sinusoid embedding
    {
        int m = tid >> 2, sub = tid & 3;
        int ec = e_s[m];
        float xs[3];
        xs[0] = frac_diff[(size_t)ec * 3 + 0];
        xs[1] = frac_diff[(size_t)ec * 3 + 1];
        xs[2] = frac_diff[(size_t)ec * 3 + 2];
#pragma unroll
        for (int d = 0; d < 3; ++d) {
            f16 sv[16], cv[16];
#pragma unroll
            for (int i = 0; i < 16; ++i) {
                float f = (float)(sub * 16 + i);
                float t = xs[d] * f;
                float rev = t - floorf(t);
                sv[i] = (f16)__builtin_amdgcn_sinf(rev);
                cv[i] = (f16)__builtin_amdgcn_cosf(rev);
            }
            f16* ps = At + m * 392 + d * 64 + sub * 16;
            ((half8*)ps)[0] = ((half8*)sv)[0];
            ((half8*)ps)[1] = ((half8*)sv)[1];
            f16* pc = ps + 192;
            ((half8*)pc)[0] = ((half8*)cv)[0];
            ((half8*)pc)[1] = ((half8*)cv)[1];
        }
    }
    __syncthreads();

    int lane = tid & 63, w = tid >> 6;
    int l15 = lane & 15, q = lane >> 4;
    const f32x4 z4 = {0.f, 0.f, 0.f, 0.f};

    // ---- GEMM1: [64 x 384] @ [384 x 256]
    f32x4 acc[4][4];
#pragma unroll
    for (int a = 0; a < 4; ++a)
#pragma unroll
        for (int b = 0; b < 4; ++b) acc[a][b] = z4;
    for (int ks = 0; ks < 12; ++ks) {
        half8 afr[4];
#pragma unroll
        for (int mb = 0; mb < 4; ++mb)
            afr[mb] = *(const half8*)(At + (mb*16 + l15) * 392 + ks*32 + q*8);
#pragma unroll
        for (int nbl = 0; nbl < 4; ++nbl) {
            int nb = w * 4 + nbl;
            half8 bfr = *(const half8*)(Wfd + ((size_t)(nb*12 + ks) * 64 + lane) * 8);
#pragma unroll
            for (int mb = 0; mb < 4; ++mb)
                acc[mb][nbl] = __builtin_amdgcn_mfma_f32_16x16x32_f16(afr[mb], bfr, acc[mb][nbl], 0, 0, 0);
        }
    }
    __syncthreads();

    // ---- epilogue 1: gather node/graph terms (f16 rows), silu -> LDS stride 264
#pragma unroll
    for (int mb = 0; mb < 4; ++mb)
#pragma unroll
        for (int rr = 0; rr < 4; ++rr) {
            int mm = mb*16 + q*4 + rr;
            int sidx = src_s[mm], didx = dst_s[mm], gidx = g_s[mm];
            const f16* p1 = Hh1 + (size_t)sidx * 256;
            const f16* p2 = Hh2 + (size_t)didx * 256;
            const float* p3 = latW + (size_t)gidx * 256;
#pragma unroll
            for (int nbl = 0; nbl < 4; ++nbl) {
                int n = (w*4 + nbl) * 16 + l15;
                float vv = acc[mb][nbl][rr] + (float)p1[n] + (float)p2[n] + p3[n];
                At[mm * 264 + n] = (f16)fast_silu(vv);
            }
        }
    __syncthreads();

    // ---- GEMM2: [64 x 256] @ [256 x 256]
    f32x4 acc2[4][4];
#pragma unroll
    for (int a = 0; a < 4; ++a)
#pragma unroll
        for (int b = 0; b < 4; ++b) acc2[a][b] = z4;
    for (int ks = 0; ks < 8; ++ks) {
        half8 afr[4];
#pragma unroll
        for (int mb = 0; mb < 4; ++mb)
            afr[mb] = *(const half8*)(At + (mb*16 + l15) * 264 + ks*32 + q*8);
#pragma unroll
        for (int nbl = 0; nbl < 4; ++nbl) {
            int nb = w * 4 + nbl;
            half8 bfr = *(const half8*)(We2 + ((size_t)(nb*8 + ks) * 64 + lane) * 8);
#pragma unroll
            for (int mb = 0; mb < 4; ++mb)
                acc2[mb][nbl] = __builtin_amdgcn_mfma_f32_16x16x32_f16(afr[mb], bfr, acc2[mb][nbl], 0, 0, 0);
        }
    }
    __syncthreads();   // At free again

    // ---- epilogue 2: silu(+eb2) -> LDS (zeros for invalid slots)
#pragma unroll
    for (int mb = 0; mb < 4; ++mb)
#pragma unroll
        for (int rr = 0; rr < 4; ++rr) {
            int mm = mb*16 + q*4 + rr;
            bool valid = (srcr[mm] >= 0);
#pragma unroll
            for (int nbl = 0; nbl < 4; ++nbl) {
                int n = (w*4 + nbl) * 16 + l15;
                float vv = valid ? fast_silu(acc2[mb][nbl][rr] + eb2[n]) : 0.f;
                At[mm * 264 + n] = (f16)vv;
            }
        }
    __syncthreads();

    // ---- segmented reduction: thread t owns column t; src runs are contiguous
    {
        int t = tid;
        float run = 0.f;
        int cur = srcr[0];
        for (int mm = 0; mm < 64; ++mm) {
            int s = srcr[mm];
            float v = (float)At[mm * 264 + t];
            if (s != cur) {
                if (cur >= 0) atomicAdd(aggsum + (size_t)cur * 256 + t, run);
                cur = s; run = v;
            } else run += v;
        }
        if (cur >= 0) atomicAdd(aggsum + (size_t)cur * 256 + t, run);
    }
}

// ---------------------------------------------------------------------------
// Node post: agg = aggsum / max(cnt,1); t = silu(Nh + agg@Wn1a + nb1);
// out = h + silu(t@Wn2 + nb2)
// ---------------------------------------------------------------------------
__global__ __launch_bounds__(256) void node_post_kernel(
    const float* __restrict__ aggsum, const int* __restrict__ cnt,
    const f16* __restrict__ Nh, const f16* __restrict__ Wn1a, const f16* __restrict__ Wn2,
    const float* __restrict__ nb1, const float* __restrict__ nb2,
    const float* __restrict__ h, float* __restrict__ out)
{
    __shared__ f16 T[64 * 264];
    int tid = threadIdx.x;
    int r = tid >> 2, c4 = tid & 3;
    int row = blockIdx.x * 64 + r;
    int rowc = min(row, N_NODES - 1);
    float inv = 1.f / fmaxf((float)cnt[rowc], 1.f);
    {
        const float* ap = aggsum + (size_t)rowc * 256 + c4 * 64;
        f16 av[64];
#pragma unroll
        for (int i = 0; i < 16; ++i) {
            float4 x = ((const float4*)ap)[i];
            av[4*i+0] = (f16)(x.x * inv);
            av[4*i+1] = (f16)(x.y * inv);
            av[4*i+2] = (f16)(x.z * inv);
            av[4*i+3] = (f16)(x.w * inv);
        }
        f16* dp = T + r * 264 + c4 * 64;
#pragma unroll
        for (int i = 0; i < 8; ++i) ((half8*)dp)[i] = ((half8*)av)[i];
    }
    __syncthreads();

    int lane = tid & 63, w = tid >> 6;
    int l15 = lane & 15, q = lane >> 4;
    const f32x4 z4 = {0.f, 0.f, 0.f, 0.f};

    f32x4 acc[4][4];
#pragma unroll
    for (int a = 0; a < 4; ++a)
#pragma unroll
        for (int b = 0; b < 4; ++b) acc[a][b] = z4;
    for (int ks = 0; ks < 8; ++ks) {
        half8 afr[4];
#pragma unroll
        for (int mb = 0; mb < 4; ++mb)
            afr[mb] = *(const half8*)(T + (mb*16 + l15) * 264 + ks*32 + q*8);
#pragma unroll
        for (int nbl = 0; nbl < 4; ++nbl) {
            int nb = w * 4 + nbl;
            half8 bfr = *(const half8*)(Wn1a + ((size_t)(nb*8 + ks) * 64 + lane) * 8);
#pragma unroll
            for (int mb = 0; mb < 4; ++mb)
                acc[mb][nbl] = __builtin_amdgcn_mfma_f32_16x16x32_f16(afr[mb], bfr, acc[mb][nbl], 0, 0, 0);
        }
    }
    __syncthreads();

#pragma unroll
    for (int mb = 0; mb < 4; ++mb)
#pragma unroll
        for (int rr = 0; rr < 4; ++rr) {
            int orow = blockIdx.x * 64 + mb*16 + q*4 + rr;
            int orc = min(orow, N_NODES - 1);
            const f16* np = Nh + (size_t)orc * 256;
            int mm = mb*16 + q*4 + rr;
#pragma unroll
            for (int nbl = 0; nbl < 4; ++nbl) {
                int n = (w*4 + nbl) * 16 + l15;
                float tv = fast_silu(acc[mb][nbl][rr] + (float)np[n] + nb1[n]);
                T[mm * 264 + n] = (f16)tv;
            }
        }
    __syncthreads();

    f32x4 acc2[4][4];
#pragma unroll
    for (int a = 0; a < 4; ++a)
#pragma unroll
        for (int b = 0; b < 4; ++b) acc2[a][b] = z4;
    for (int ks = 0; ks < 8; ++ks) {
        half8 afr[4];
#pragma unroll
        for (int mb = 0; mb < 4; ++mb)
            afr[mb] = *(const half8*)(T + (mb*16 + l15) * 264 + ks*32 + q*8);
#pragma unroll
        for (int nbl = 0; nbl < 4; ++nbl) {
            int nb = w * 4 + nbl;
            half8 bfr = *(const half8*)(Wn2 + ((size_t)(nb*8 + ks) * 64 + lane) * 8);
#pragma unroll
            for (int mb = 0; mb < 4; ++mb)
                acc2[mb][nbl] = __builtin_amdgcn_mfma_f32_16x16x32_f16(afr[mb], bfr, acc2[mb][nbl], 0, 0, 0);
        }
    }

#pragma unroll
    for (int mb = 0; mb < 4; ++mb)
#pragma unroll
        for (int rr = 0; rr < 4; ++rr) {
            int orow = blockIdx.x * 64 + mb*16 + q*4 + rr;
            if (orow < N_NODES) {
#pragma unroll
                for (int nbl = 0; nbl < 4; ++nbl) {
                    int n = (w*4 + nbl) * 16 + l15;
                    float ov = h[(size_t)orow * 256 + n] + fast_silu(acc2[mb][nbl][rr] + nb2[n]);
                    out[(size_t)orow * 256 + n] = ov;
                }
            }
        }
}

// ---------------------------------------------------------------------------
extern "C" void kernel_launch(void* const* d_in, const int* in_sizes, int n_in,
                              void* d_out, int out_size, void* d_ws, size_t ws_size,
                              hipStream_t stream) {
    const float* h          = (const float*)d_in[0];
    const float* lattices   = (const float*)d_in[2];
    const int*   edge_index = (const int*)d_in[3];
    const int*   edge2graph = (const int*)d_in[4];
    const float* frac_diff  = (const float*)d_in[5];
    const float* ln_gamma   = (const float*)d_in[6];
    const float* ln_beta    = (const float*)d_in[7];
    const float* eW1        = (const float*)d_in[8];
    const float* eb1        = (const float*)d_in[9];
    const float* eW2        = (const float*)d_in[10];
    const float* eb2        = (const float*)d_in[11];
    const float* nW1        = (const float*)d_in[12];
    const float* nb1        = (const float*)d_in[13];
    const float* nW2        = (const float*)d_in[14];
    const float* nb2        = (const float*)d_in[15];
    float* out = (float*)d_out;
    char* base = (char*)d_ws;

    // workspace layout (byte offsets)
    float* aggsum   = (float*)(base + 0);              // 12.8M f32 = 51,200,000 B
    float* latW     = (float*)(base + 51200000);       // 32768 f32
    int*   cnt      = (int*)  (base + 51331072);       // 50176 int
    int*   off      = (int*)  (base + 51531776);       // 50176 int
    int*   tmp      = (int*)  (base + 51732480);       // 50176 int
    int*   sorted_e = (int*)  (base + 51933184);       // 500000 int
    f16*   Hh1      = (f16*)  (base + 53933184);       // 12.8M f16
    f16*   Hh2      = (f16*)  (base + 79533184);
    f16*   Nh       = (f16*)  (base + 105133184);
    f16*   packs    = (f16*)  (base + 130733184);
    f16* Wfd  = packs;            // 98,304 halfs (K=384)
    f16* Whi  = Wfd  + 98304;
    f16* Whj  = Whi  + 65536;
    f16* We2  = Whj  + 65536;
    f16* Wn1h = We2  + 65536;
    f16* Wn1a = Wn1h + 65536;
    f16* Wn2  = Wn1a + 65536;     // ends at byte 131,716,224
    if (ws_size < (size_t)131716224) return;

    // zero aggsum + cnt + off + tmp (latW in range gets overwritten by prep)
    hipMemsetAsync(base, 0, (size_t)51933184, stream);

    pack_weight<<<48, 256, 0, stream>>>(eW1 + 521 * 256, Wfd, 12);
    pack_weight<<<32, 256, 0, stream>>>(eW1,             Whi, 8);
    pack_weight<<<32, 256, 0, stream>>>(eW1 + 256 * 256, Whj, 8);
    pack_weight<<<32, 256, 0, stream>>>(eW2,             We2, 8);
    pack_weight<<<32, 256, 0, stream>>>(nW1,             Wn1h, 8);
    pack_weight<<<32, 256, 0, stream>>>(nW1 + 256 * 256, Wn1a, 8);
    pack_weight<<<32, 256, 0, stream>>>(nW2,             Wn2, 8);
    prep_latw<<<G_GRAPHS, 256, 0, stream>>>(lattices, eW1, eb1, latW);

    hist_kernel<<<(E_EDGES + 255) / 256, 256, 0, stream>>>(edge_index, cnt);
    scan_kernel<<<1, 1024, 0, stream>>>(cnt, off);
    pos_kernel<<<(E_EDGES + 255) / 256, 256, 0, stream>>>(edge_index, off, tmp, sorted_e);

    ln_gemm_kernel<<<(N_NODES + 63) / 64, 256, 0, stream>>>(
        h, ln_gamma, ln_beta, Whi, Whj, Wn1h, Hh1, Hh2, Nh);

    edge_kernel<<<(E_EDGES + 63) / 64, 256, 0, stream>>>(
        sorted_e, edge_index, edge2graph, frac_diff, Hh1, Hh2, latW, Wfd, We2, eb2, aggsum);

    node_post_kernel<<<(N_NODES + 63) / 64, 256, 0, stream>>>(
        aggsum, cnt, Nh, Wn1a, Wn2, nb1, nb2, h, out);
}